// Round 2
// baseline (100.614 us; speedup 1.0000x reference)
//
#include <hip/hip_runtime.h>

typedef __attribute__((ext_vector_type(8))) short short8;
typedef __attribute__((ext_vector_type(4))) float f32x4;

// Manual fp32 -> bf16 bits, round-to-nearest-even (finite values only).
__device__ __forceinline__ unsigned short bf16_bits(float f) {
  unsigned int u = __float_as_uint(f);
  return (unsigned short)((u + 0x7FFFu + ((u >> 16) & 1u)) >> 16);
}

// ---------------------------------------------------------------------------
// Precompute: hx[512][256] = x @ W1[:128]          (fp32)
//             hy[512][256] = y @ W1[128:] + b1     (fp32)
//             W2T[n][k]    = bf16(W2[k][n])        (bf16 bits as ushort)
// ---------------------------------------------------------------------------
__global__ void k_pre(const float* __restrict__ x, const float* __restrict__ y,
                      const float* __restrict__ W1, const float* __restrict__ b1,
                      const float* __restrict__ W2,
                      float* __restrict__ hx, float* __restrict__ hy,
                      unsigned short* __restrict__ W2T) {
  const int b = blockIdx.x;
  const int t = threadIdx.x;
  if (b < 128) {
    const bool isx = (b < 64);
    const int i0 = (isx ? b : (b - 64)) * 8;
    const float* __restrict__ src = isx ? x : y;
    const float* __restrict__ W = W1 + (isx ? 0 : 128 * 256);
    float acc[8];
    const float binit = isx ? 0.0f : b1[t];
#pragma unroll
    for (int r = 0; r < 8; ++r) acc[r] = binit;
    for (int d = 0; d < 128; ++d) {
      const float wv = W[d * 256 + t];  // coalesced across t
#pragma unroll
      for (int r = 0; r < 8; ++r) acc[r] += src[(i0 + r) * 128 + d] * wv;  // uniform loads
    }
    float* __restrict__ dst = isx ? hx : hy;
#pragma unroll
    for (int r = 0; r < 8; ++r) dst[(i0 + r) * 256 + t] = acc[r];
  } else {
    const int n = b - 128;
    W2T[n * 256 + t] = bf16_bits(W2[t * 256 + n]);
  }
}

// ---------------------------------------------------------------------------
// Main fused kernel, v2.
// Block = 512 threads (8 waves). Grid = 512 blocks = (ig 0..63) x (j0-tile 0..7).
// Block computes 8 i's (ig*8..+7) x 64 j's (j0..j0+63) x full N=256.
// Wave w owns N-cols [w*32, w*32+32); its B slice (32 cols x 256 K, bf16)
// lives in 16 short8 register fragments for the whole kernel (loaded once).
// Per i: A_lds[64][264] bf16 with A[r][k] = relu(hx[i][k] + hy[j0+r][k]);
// K-loop = 8 steps x (4 ds_read_b128 + 8 MFMA), no barriers inside.
// MFMA v_mfma_f32_16x16x32_bf16 frag layout (verified in R1):
//   A: row = lane&15, k = 8*(lane>>4)+e ; B: col = lane&15, k = 8*(lane>>4)+e
//   C: col = lane&15, row = 4*(lane>>4)+reg
// Epilogue fused: relu(C+b2).W3, shfl-reduce over 16 lanes, LDS cross-wave
// reduce (8 partials), coalesced 64-float store per i.
// ---------------------------------------------------------------------------
__launch_bounds__(512, 4)
__global__ void k_main(const float* __restrict__ hx, const float* __restrict__ hy,
                       const unsigned short* __restrict__ W2T,
                       const float* __restrict__ b2, const float* __restrict__ W3,
                       const float* __restrict__ b3, float* __restrict__ out) {
  __shared__ unsigned short A_lds[64 * 264];  // 33792 B, row pad +8 (132 dw = 4 mod 32)
  __shared__ float hx_all[8 * 288];           // 9216 B: [g][s*36 + t], s=k>>5, t=k&31
  __shared__ float red[64 * 8];               // 2048 B

  const int tid = threadIdx.x;
  const int lane = tid & 63;
  const int w = tid >> 6;        // wave id 0..7 -> n-slice w*32
  const int l15 = lane & 15;
  const int l4 = lane >> 4;
  const int ig = blockIdx.x >> 3;
  const int j0 = (blockIdx.x & 7) * 64;
  const int i0 = ig * 8;

  // ---- persistent B fragments (16 x short8 = 64 VGPRs), from L2 ----
  short8 bq[8][2];  // [kk][nf]
  {
    const unsigned short* bb = W2T + (w * 32 + l15) * 256 + l4 * 8;
#pragma unroll
    for (int kk = 0; kk < 8; ++kk) {
#pragma unroll
      for (int nf = 0; nf < 2; ++nf)
        bq[kk][nf] = *reinterpret_cast<const short8*>(bb + nf * 4096 + kk * 32);
    }
  }

  // ---- preload all 8 hx rows into padded LDS (conflict-free fragment reads) ----
#pragma unroll
  for (int r = 0; r < 4; ++r) {
    const int idx = r * 512 + tid;        // 0..2047
    const int g = idx >> 8;
    const int t = idx & 255;
    hx_all[g * 288 + (t >> 5) * 36 + (t & 31)] = hx[(i0 + g) * 256 + t];
  }

  // epilogue constants
  float b2v[2], w3v[2];
#pragma unroll
  for (int nf = 0; nf < 2; ++nf) {
    const int c = w * 32 + nf * 16 + l15;
    b2v[nf] = b2[c];
    w3v[nf] = W3[c];
  }
  const float b3v = b3[0];

  __syncthreads();  // hx_all ready

#pragma unroll 1
  for (int g = 0; g < 8; ++g) {
    // ---- A-gen: wave w fills rows w*8..w*8+7; lane covers 16B k-chunk ----
    {
      const float4 xv = *reinterpret_cast<const float4*>(
          &hx_all[g * 288 + (lane >> 3) * 36 + (lane & 7) * 4]);
#pragma unroll
      for (int c = 0; c < 8; ++c) {
        const int row = w * 8 + c;
        const float4 hv = *reinterpret_cast<const float4*>(
            &hy[(j0 + row) * 256 + lane * 4]);  // 1KB/wave, coalesced
        const float a0 = fmaxf(hv.x + xv.x, 0.0f);
        const float a1 = fmaxf(hv.y + xv.y, 0.0f);
        const float a2 = fmaxf(hv.z + xv.z, 0.0f);
        const float a3 = fmaxf(hv.w + xv.w, 0.0f);
        uint2 pk;
        pk.x = (unsigned int)bf16_bits(a0) | ((unsigned int)bf16_bits(a1) << 16);
        pk.y = (unsigned int)bf16_bits(a2) | ((unsigned int)bf16_bits(a3) << 16);
        *reinterpret_cast<uint2*>(&A_lds[row * 264 + lane * 4]) = pk;
      }
    }
    __syncthreads();  // A ready

    f32x4 acc[4][2];
#pragma unroll
    for (int mf = 0; mf < 4; ++mf)
#pragma unroll
      for (int nf = 0; nf < 2; ++nf) acc[mf][nf] = (f32x4){0.f, 0.f, 0.f, 0.f};

#pragma unroll
    for (int kk = 0; kk < 8; ++kk) {
      short8 af[4];
#pragma unroll
      for (int mf = 0; mf < 4; ++mf)
        af[mf] = *reinterpret_cast<const short8*>(
            &A_lds[(mf * 16 + l15) * 264 + kk * 32 + l4 * 8]);
#pragma unroll
      for (int mf = 0; mf < 4; ++mf)
#pragma unroll
        for (int nf = 0; nf < 2; ++nf)
          acc[mf][nf] = __builtin_amdgcn_mfma_f32_16x16x32_bf16(
              af[mf], bq[kk][nf], acc[mf][nf], 0, 0, 0);
    }

    // ---- fused epilogue: relu(C+b2) . W3 ----
#pragma unroll
    for (int mf = 0; mf < 4; ++mf) {
#pragma unroll
      for (int reg = 0; reg < 4; ++reg) {
        float p = fmaxf(acc[mf][0][reg] + b2v[0], 0.0f) * w3v[0] +
                  fmaxf(acc[mf][1][reg] + b2v[1], 0.0f) * w3v[1];
#pragma unroll
        for (int m = 1; m < 16; m <<= 1) p += __shfl_xor(p, m, 64);
        if (l15 == 0) red[(mf * 16 + l4 * 4 + reg) * 8 + w] = p;
      }
    }
    __syncthreads();  // red ready (also guards A_lds rewrite next g)
    if (tid < 64) {
      float s = b3v;
#pragma unroll
      for (int w8 = 0; w8 < 8; ++w8) s += red[tid * 8 + w8];
      out[(i0 + g) * 512 + j0 + tid] = s;
    }
  }
}

extern "C" void kernel_launch(void* const* d_in, const int* in_sizes, int n_in,
                              void* d_out, int out_size, void* d_ws, size_t ws_size,
                              hipStream_t stream) {
  const float* x  = (const float*)d_in[0];
  const float* y  = (const float*)d_in[1];
  const float* W1 = (const float*)d_in[2];
  const float* b1 = (const float*)d_in[3];
  const float* W2 = (const float*)d_in[4];
  const float* b2 = (const float*)d_in[5];
  const float* W3 = (const float*)d_in[6];
  const float* b3 = (const float*)d_in[7];
  float* out = (float*)d_out;

  char* ws = (char*)d_ws;
  float* hx = (float*)ws;                                   // 524288 B
  float* hy = (float*)(ws + 524288);                        // 524288 B
  unsigned short* W2T = (unsigned short*)(ws + 1048576);    // 131072 B

  k_pre<<<384, 256, 0, stream>>>(x, y, W1, b1, W2, hx, hy, W2T);
  k_main<<<512, 512, 0, stream>>>(hx, hy, W2T, b2, W3, b3, out);
}

// Round 3
// 75.389 us; speedup vs baseline: 1.3346x; 1.3346x over previous
//
#include <hip/hip_runtime.h>
#include <hip/hip_bf16.h>

typedef __attribute__((ext_vector_type(8))) short short8;
typedef __attribute__((ext_vector_type(4))) float f32x4;

// Manual fp32 -> bf16 bits, round-to-nearest-even (finite values only).
__device__ __forceinline__ unsigned short bf16_bits(float f) {
  unsigned int u = __float_as_uint(f);
  return (unsigned short)((u + 0x7FFFu + ((u >> 16) & 1u)) >> 16);
}

// Packed pair fp32 -> 2x bf16 (RTNE), as one uint.
__device__ __forceinline__ unsigned int pack_bf16(float a, float b) {
  float2 t; t.x = a; t.y = b;
  __hip_bfloat162 h = __float22bfloat162_rn(t);
  return *reinterpret_cast<unsigned int*>(&h);
}

// ---------------------------------------------------------------------------
// Precompute: hx[512][256] = x @ W1[:128]          (fp32)
//             hy[512][256] = y @ W1[128:] + b1     (fp32)
//             W2T[n][k]    = bf16(W2[k][n])        (bf16 bits as ushort)
// ---------------------------------------------------------------------------
__global__ void k_pre(const float* __restrict__ x, const float* __restrict__ y,
                      const float* __restrict__ W1, const float* __restrict__ b1,
                      const float* __restrict__ W2,
                      float* __restrict__ hx, float* __restrict__ hy,
                      unsigned short* __restrict__ W2T) {
  const int b = blockIdx.x;
  const int t = threadIdx.x;
  if (b < 128) {
    const bool isx = (b < 64);
    const int i0 = (isx ? b : (b - 64)) * 8;
    const float* __restrict__ src = isx ? x : y;
    const float* __restrict__ W = W1 + (isx ? 0 : 128 * 256);
    float acc[8];
    const float binit = isx ? 0.0f : b1[t];
#pragma unroll
    for (int r = 0; r < 8; ++r) acc[r] = binit;
    for (int d = 0; d < 128; ++d) {
      const float wv = W[d * 256 + t];  // coalesced across t
#pragma unroll
      for (int r = 0; r < 8; ++r) acc[r] += src[(i0 + r) * 128 + d] * wv;  // uniform loads
    }
    float* __restrict__ dst = isx ? hx : hy;
#pragma unroll
    for (int r = 0; r < 8; ++r) dst[(i0 + r) * 256 + t] = acc[r];
  } else {
    const int n = b - 128;
    W2T[n * 256 + t] = bf16_bits(W2[t * 256 + n]);
  }
}

// ---------------------------------------------------------------------------
// Main fused kernel, v3.
// Block = 512 threads (8 waves), grid = 512 (ig 0..63 x j-tile 0..7).
// Block: 8 i's x 64 j's x N=256. 1 block/CU (by VGPR), 2 serial rounds.
// Wave w: rows rh*32..+31 (rh=w>>2), cols cq*64..+63 (cq=w&3).
//   bq[8][4] short8 = 128 VGPR: W2T cols, resident whole kernel (NO spill:
//   launch_bounds(512,2) -> 256-VGPR cap).
//   hv[8] float4 = 32 VGPR: hy rows w*8..w*8+7 for A-gen, loaded once.
// Per g: K-loop (2 ds_read_b128 -> 8 MFMA per kk, 64 MFMA/wave), then
// A-gen(g+1) into the other A_lds buffer (hides under MFMA), then epilogue.
// ONE barrier per g (A_lds and red are double-buffered).
// MFMA v_mfma_f32_16x16x32_bf16 frag layout (verified R1):
//   A: row=l15, k=8*l4+e ; B: col=l15, k=8*l4+e ; C: col=l15, row=4*l4+reg
// ---------------------------------------------------------------------------
__launch_bounds__(512, 2)
__global__ void k_main(const float* __restrict__ hx, const float* __restrict__ hy,
                       const unsigned short* __restrict__ W2T,
                       const float* __restrict__ b2, const float* __restrict__ W3,
                       const float* __restrict__ b3, float* __restrict__ out) {
  __shared__ unsigned short A_lds[2][64 * 264];  // 2 x 33792 B, row pad +8
  __shared__ float red[2][64 * 4];               // 2 x 1024 B

  const int tid = threadIdx.x;
  const int lane = tid & 63;
  const int w = tid >> 6;
  const int l15 = lane & 15;
  const int l4 = lane >> 4;
  const int rh = w >> 2;   // row-half: rows rh*32 .. +31
  const int cq = w & 3;    // col-quarter: cols cq*64 .. +63
  const int ig = blockIdx.x >> 3;
  const int j0 = (blockIdx.x & 7) * 64;
  const int i0 = ig * 8;

  // ---- persistent B fragments: bq[kk][nf], col = cq*64+nf*16+l15, k = kk*32+l4*8
  short8 bq[8][4];
  {
    const unsigned short* bb = W2T + (cq * 64 + l15) * 256 + l4 * 8;
#pragma unroll
    for (int nf = 0; nf < 4; ++nf)
#pragma unroll
      for (int kk = 0; kk < 8; ++kk)
        bq[kk][nf] = *reinterpret_cast<const short8*>(bb + nf * 16 * 256 + kk * 32);
  }

  // ---- hy rows for A-gen (wave fills A rows w*8..w*8+7; lane covers k=lane*4..+3)
  float4 hv[8];
#pragma unroll
  for (int r = 0; r < 8; ++r)
    hv[r] = *reinterpret_cast<const float4*>(&hy[(j0 + w * 8 + r) * 256 + lane * 4]);

  // ---- epilogue constants
  float b2v[4], w3v[4];
#pragma unroll
  for (int nf = 0; nf < 4; ++nf) {
    b2v[nf] = b2[cq * 64 + nf * 16 + l15];
    w3v[nf] = W3[cq * 64 + nf * 16 + l15];
  }
  const float b3v = b3[0];

  // ---- A-gen for g = 0 into buffer 0
  {
    const float4 xv = *reinterpret_cast<const float4*>(&hx[i0 * 256 + lane * 4]);
#pragma unroll
    for (int r = 0; r < 8; ++r) {
      uint2 pk;
      pk.x = pack_bf16(fmaxf(hv[r].x + xv.x, 0.f), fmaxf(hv[r].y + xv.y, 0.f));
      pk.y = pack_bf16(fmaxf(hv[r].z + xv.z, 0.f), fmaxf(hv[r].w + xv.w, 0.f));
      *reinterpret_cast<uint2*>(&A_lds[0][(w * 8 + r) * 264 + lane * 4]) = pk;
    }
  }
  __syncthreads();

#pragma unroll 1
  for (int g = 0; g < 8; ++g) {
    const int buf = g & 1;

    f32x4 acc[2][4];
#pragma unroll
    for (int mf = 0; mf < 2; ++mf)
#pragma unroll
      for (int nf = 0; nf < 4; ++nf) acc[mf][nf] = (f32x4){0.f, 0.f, 0.f, 0.f};

    // ---- K-loop: 16 ds_read_b128 + 64 MFMA, no barriers ----
#pragma unroll
    for (int kk = 0; kk < 8; ++kk) {
      short8 af[2];
#pragma unroll
      for (int mf = 0; mf < 2; ++mf)
        af[mf] = *reinterpret_cast<const short8*>(
            &A_lds[buf][(rh * 32 + mf * 16 + l15) * 264 + kk * 32 + l4 * 8]);
#pragma unroll
      for (int mf = 0; mf < 2; ++mf)
#pragma unroll
        for (int nf = 0; nf < 4; ++nf)
          acc[mf][nf] = __builtin_amdgcn_mfma_f32_16x16x32_bf16(
              af[mf], bq[kk][nf], acc[mf][nf], 0, 0, 0);
    }

    // ---- A-gen for g+1 into the other buffer (overlaps with MFMA above) ----
    if (g < 7) {
      const float4 xv = *reinterpret_cast<const float4*>(&hx[(i0 + g + 1) * 256 + lane * 4]);
#pragma unroll
      for (int r = 0; r < 8; ++r) {
        uint2 pk;
        pk.x = pack_bf16(fmaxf(hv[r].x + xv.x, 0.f), fmaxf(hv[r].y + xv.y, 0.f));
        pk.y = pack_bf16(fmaxf(hv[r].z + xv.z, 0.f), fmaxf(hv[r].w + xv.w, 0.f));
        *reinterpret_cast<uint2*>(&A_lds[1 - buf][(w * 8 + r) * 264 + lane * 4]) = pk;
      }
    }

    // ---- fused epilogue: relu(C+b2) . W3, 16-lane reduce, cross-wave via red ----
#pragma unroll
    for (int mf = 0; mf < 2; ++mf) {
#pragma unroll
      for (int reg = 0; reg < 4; ++reg) {
        float p = 0.f;
#pragma unroll
        for (int nf = 0; nf < 4; ++nf)
          p += fmaxf(acc[mf][nf][reg] + b2v[nf], 0.f) * w3v[nf];
#pragma unroll
        for (int m = 1; m < 16; m <<= 1) p += __shfl_xor(p, m, 64);
        if (l15 == 0) red[buf][(rh * 32 + mf * 16 + l4 * 4 + reg) * 4 + cq] = p;
      }
    }
    __syncthreads();  // red ready AND A_lds[1-buf] fully written for next g

    if (tid < 64) {
      const float s = red[buf][tid * 4 + 0] + red[buf][tid * 4 + 1] +
                      red[buf][tid * 4 + 2] + red[buf][tid * 4 + 3] + b3v;
      out[(i0 + g) * 512 + j0 + tid] = s;
    }
  }
}

extern "C" void kernel_launch(void* const* d_in, const int* in_sizes, int n_in,
                              void* d_out, int out_size, void* d_ws, size_t ws_size,
                              hipStream_t stream) {
  const float* x  = (const float*)d_in[0];
  const float* y  = (const float*)d_in[1];
  const float* W1 = (const float*)d_in[2];
  const float* b1 = (const float*)d_in[3];
  const float* W2 = (const float*)d_in[4];
  const float* b2 = (const float*)d_in[5];
  const float* W3 = (const float*)d_in[6];
  const float* b3 = (const float*)d_in[7];
  float* out = (float*)d_out;

  char* ws = (char*)d_ws;
  float* hx = (float*)ws;                                   // 524288 B
  float* hy = (float*)(ws + 524288);                        // 524288 B
  unsigned short* W2T = (unsigned short*)(ws + 1048576);    // 131072 B

  k_pre<<<384, 256, 0, stream>>>(x, y, W1, b1, W2, hx, hy, W2T);
  k_main<<<512, 512, 0, stream>>>(hx, hy, W2T, b2, W3, b3, out);
}

// Round 4
// 54.523 us; speedup vs baseline: 1.8453x; 1.3827x over previous
//
#include <hip/hip_runtime.h>
#include <hip/hip_bf16.h>

typedef __attribute__((ext_vector_type(8))) short short8;
typedef __attribute__((ext_vector_type(4))) float f32x4;

// Manual fp32 -> bf16 bits, round-to-nearest-even (finite values only).
__device__ __forceinline__ unsigned short bf16_bits(float f) {
  unsigned int u = __float_as_uint(f);
  return (unsigned short)((u + 0x7FFFu + ((u >> 16) & 1u)) >> 16);
}

// Packed pair fp32 -> 2x bf16 (RTNE), as one uint (v_cvt_pk_bf16_f32).
__device__ __forceinline__ unsigned int pack_bf16(float a, float b) {
  float2 t; t.x = a; t.y = b;
  __hip_bfloat162 h = __float22bfloat162_rn(t);
  return *reinterpret_cast<unsigned int*>(&h);
}

// ---------------------------------------------------------------------------
// Precompute: hx[512][256] = x @ W1[:128]          (fp32)
//             hy[512][256] = y @ W1[128:] + b1     (fp32)
//             W2T[n][k]    = bf16(W2[k][n])        (bf16 bits as ushort)
// ---------------------------------------------------------------------------
__global__ void k_pre(const float* __restrict__ x, const float* __restrict__ y,
                      const float* __restrict__ W1, const float* __restrict__ b1,
                      const float* __restrict__ W2,
                      float* __restrict__ hx, float* __restrict__ hy,
                      unsigned short* __restrict__ W2T) {
  const int b = blockIdx.x;
  const int t = threadIdx.x;
  if (b < 128) {
    const bool isx = (b < 64);
    const int i0 = (isx ? b : (b - 64)) * 8;
    const float* __restrict__ src = isx ? x : y;
    const float* __restrict__ W = W1 + (isx ? 0 : 128 * 256);
    float acc[8];
    const float binit = isx ? 0.0f : b1[t];
#pragma unroll
    for (int r = 0; r < 8; ++r) acc[r] = binit;
    for (int d = 0; d < 128; ++d) {
      const float wv = W[d * 256 + t];  // coalesced across t
#pragma unroll
      for (int r = 0; r < 8; ++r) acc[r] += src[(i0 + r) * 128 + d] * wv;  // uniform loads
    }
    float* __restrict__ dst = isx ? hx : hy;
#pragma unroll
    for (int r = 0; r < 8; ++r) dst[(i0 + r) * 256 + t] = acc[r];
  } else {
    const int n = b - 128;
    W2T[n * 256 + t] = bf16_bits(W2[t * 256 + n]);
  }
}

// ---------------------------------------------------------------------------
// Main fused kernel, v4.
// Block = 256 threads (4 waves), grid = 512 (ig 0..63 x j-tile 0..7).
// Block: 8 i's x 64 j's x N=256. TWO independent blocks/CU (anti-phased ->
// one block's MFMA overlaps the other's A-gen/epilogue).
// Wave w: ALL 64 rows (mf=4), cols w*64..+63 (nf=4).
//   bq[8][4] short8 = 128 VGPR resident; acc[4][4] = 64; ~225 total/wave.
// Per g:
//   K-loop: 8 kk x (4 ds_read_b128 + 16 MFMA), setprio(1) around MFMA.
//   Epilogue: p = relu(acc+b2).w3 per (mf,reg), direct LDS write to
//             part[64][68] (2-way banks, NO shuffles).
//   bar1 -> [256-thread final reduce + store(g)] || [A-gen(g+1)] -> bar2.
// A-gen: wave w writes rows w*16..+15 of A_lds (row pad +8): 16 batched
//   1KB-coalesced hy loads, add hx, relu, cvt_pk, b64 writes (2-way banks).
// MFMA v_mfma_f32_16x16x32_bf16 frag layout (verified R1):
//   A: row=l15, k=8*l4+e ; B: col=l15, k=8*l4+e ; C: col=l15, row=4*l4+reg
// ---------------------------------------------------------------------------
__launch_bounds__(256, 2)
__global__ void k_main(const float* __restrict__ hx, const float* __restrict__ hy,
                       const unsigned short* __restrict__ W2T,
                       const float* __restrict__ b2, const float* __restrict__ W3,
                       const float* __restrict__ b3, float* __restrict__ out) {
  __shared__ unsigned short A_lds[64 * 264];  // 33792 B
  __shared__ float part[64 * 68];             // 17408 B

  const int tid = threadIdx.x;
  const int lane = tid & 63;
  const int w = tid >> 6;        // wave 0..3 -> col slice w*64
  const int l15 = lane & 15;
  const int l4 = lane >> 4;
  const int ig = blockIdx.x >> 3;
  const int j0 = (blockIdx.x & 7) * 64;
  const int i0 = ig * 8;

  // ---- persistent B fragments: col = w*64+nf*16+l15, k = kk*32+l4*8 ----
  short8 bq[8][4];
  {
    const unsigned short* bb = W2T + (w * 64 + l15) * 256 + l4 * 8;
#pragma unroll
    for (int nf = 0; nf < 4; ++nf)
#pragma unroll
      for (int kk = 0; kk < 8; ++kk)
        bq[kk][nf] = *reinterpret_cast<const short8*>(bb + nf * 16 * 256 + kk * 32);
  }

  // ---- epilogue constants ----
  float b2v[4], w3v[4];
#pragma unroll
  for (int nf = 0; nf < 4; ++nf) {
    b2v[nf] = b2[w * 64 + nf * 16 + l15];
    w3v[nf] = W3[w * 64 + nf * 16 + l15];
  }
  const float b3v = b3[0];

  // ---- A-gen for i = i0 (wave w -> rows w*16..+15; lane -> k = lane*4..+3) ----
  {
    const float4 xv = *reinterpret_cast<const float4*>(&hx[i0 * 256 + lane * 4]);
    float4 hv[16];
#pragma unroll
    for (int r = 0; r < 16; ++r)
      hv[r] = *reinterpret_cast<const float4*>(&hy[(j0 + w * 16 + r) * 256 + lane * 4]);
#pragma unroll
    for (int r = 0; r < 16; ++r) {
      uint2 pk;
      pk.x = pack_bf16(fmaxf(hv[r].x + xv.x, 0.f), fmaxf(hv[r].y + xv.y, 0.f));
      pk.y = pack_bf16(fmaxf(hv[r].z + xv.z, 0.f), fmaxf(hv[r].w + xv.w, 0.f));
      *reinterpret_cast<uint2*>(&A_lds[(w * 16 + r) * 264 + lane * 4]) = pk;
    }
  }
  __syncthreads();

#pragma unroll 1
  for (int g = 0; g < 8; ++g) {
    f32x4 acc[4][4];
#pragma unroll
    for (int mf = 0; mf < 4; ++mf)
#pragma unroll
      for (int nf = 0; nf < 4; ++nf) acc[mf][nf] = (f32x4){0.f, 0.f, 0.f, 0.f};

    // ---- K-loop: 32 ds_read_b128 + 128 MFMA, no barriers ----
    __builtin_amdgcn_s_setprio(1);
#pragma unroll
    for (int kk = 0; kk < 8; ++kk) {
      short8 af[4];
#pragma unroll
      for (int mf = 0; mf < 4; ++mf)
        af[mf] = *reinterpret_cast<const short8*>(
            &A_lds[(mf * 16 + l15) * 264 + kk * 32 + l4 * 8]);
#pragma unroll
      for (int mf = 0; mf < 4; ++mf)
#pragma unroll
        for (int nf = 0; nf < 4; ++nf)
          acc[mf][nf] = __builtin_amdgcn_mfma_f32_16x16x32_bf16(
              af[mf], bq[kk][nf], acc[mf][nf], 0, 0, 0);
    }
    __builtin_amdgcn_s_setprio(0);

    // ---- epilogue: p = relu(acc+b2).w3 summed over nf, direct LDS write ----
#pragma unroll
    for (int mf = 0; mf < 4; ++mf) {
#pragma unroll
      for (int reg = 0; reg < 4; ++reg) {
        float p = 0.f;
#pragma unroll
        for (int nf = 0; nf < 4; ++nf)
          p += fmaxf(acc[mf][nf][reg] + b2v[nf], 0.f) * w3v[nf];
        part[(mf * 16 + l4 * 4 + reg) * 68 + w * 16 + l15] = p;  // 2-way banks
      }
    }
    __syncthreads();  // bar1: part ready, A_lds reads done

    // ---- final reduce + store(g): row = tid>>2, seg = tid&3 ----
    {
      const int row = tid >> 2;
      const int seg = tid & 3;
      const f32x4* pp = reinterpret_cast<const f32x4*>(&part[row * 68 + seg * 16]);
      f32x4 v0 = pp[0], v1 = pp[1], v2 = pp[2], v3 = pp[3];
      float p = (v0[0] + v0[1] + v0[2] + v0[3]) + (v1[0] + v1[1] + v1[2] + v1[3]) +
                (v2[0] + v2[1] + v2[2] + v2[3]) + (v3[0] + v3[1] + v3[2] + v3[3]);
      p += __shfl_xor(p, 1, 64);
      p += __shfl_xor(p, 2, 64);
      if (seg == 0) out[(i0 + g) * 512 + j0 + row] = p + b3v;
    }

    // ---- A-gen for g+1 (overlaps with store above; other block MFMAs) ----
    if (g < 7) {
      const float4 xv = *reinterpret_cast<const float4*>(&hx[(i0 + g + 1) * 256 + lane * 4]);
      float4 hv[16];
#pragma unroll
      for (int r = 0; r < 16; ++r)
        hv[r] = *reinterpret_cast<const float4*>(&hy[(j0 + w * 16 + r) * 256 + lane * 4]);
#pragma unroll
      for (int r = 0; r < 16; ++r) {
        uint2 pk;
        pk.x = pack_bf16(fmaxf(hv[r].x + xv.x, 0.f), fmaxf(hv[r].y + xv.y, 0.f));
        pk.y = pack_bf16(fmaxf(hv[r].z + xv.z, 0.f), fmaxf(hv[r].w + xv.w, 0.f));
        *reinterpret_cast<uint2*>(&A_lds[(w * 16 + r) * 264 + lane * 4]) = pk;
      }
      __syncthreads();  // bar2: A_lds(g+1) ready, part safe to overwrite
    }
  }
}

extern "C" void kernel_launch(void* const* d_in, const int* in_sizes, int n_in,
                              void* d_out, int out_size, void* d_ws, size_t ws_size,
                              hipStream_t stream) {
  const float* x  = (const float*)d_in[0];
  const float* y  = (const float*)d_in[1];
  const float* W1 = (const float*)d_in[2];
  const float* b1 = (const float*)d_in[3];
  const float* W2 = (const float*)d_in[4];
  const float* b2 = (const float*)d_in[5];
  const float* W3 = (const float*)d_in[6];
  const float* b3 = (const float*)d_in[7];
  float* out = (float*)d_out;

  char* ws = (char*)d_ws;
  float* hx = (float*)ws;                                   // 524288 B
  float* hy = (float*)(ws + 524288);                        // 524288 B
  unsigned short* W2T = (unsigned short*)(ws + 1048576);    // 131072 B

  k_pre<<<384, 256, 0, stream>>>(x, y, W1, b1, W2, hx, hy, W2T);
  k_main<<<512, 256, 0, stream>>>(hx, hy, W2T, b2, W3, b3, out);
}